// Round 1
// baseline (430.916 us; speedup 1.0000x reference)
//
#include <hip/hip_runtime.h>
#include <float.h>

// Top-left corner pooling, fused: out = 2 * rev_cummax_W(rev_cummax_H(x))
// x: (16, 256, 128, 128) fp32 NCHW -> 4096 independent 128x128 planes.
//
// Layout: each 32-lane half-wave owns one plane. Lane l holds columns
// 4l..4l+3 as a float4. Iterate h = 127..0:
//   - coalesced float4 row load (16 B/lane, 512 B per half-wave)
//   - running per-column max (H suffix scan, loop-carried)
//   - W suffix scan fully in-register: intra-float4 suffix max +
//     5-step shfl_down(width=32) doubling + 1 exclusive shift
//   - coalesced float4 store of 2*result
// No LDS, single pass, minimum HBM traffic (1R + 1W per element).

__global__ __launch_bounds__(256) void corner_pool_kernel(
    const float* __restrict__ x, float* __restrict__ out, int planes) {
  constexpr int H = 128;
  constexpr int W = 128;
  constexpr int WV = W / 4;  // float4s per row = 32

  const int lane32 = threadIdx.x & 31;
  const int group = (blockIdx.x * blockDim.x + threadIdx.x) >> 5;
  if (group >= planes) return;

  const float4* __restrict__ xin =
      (const float4*)(x + (size_t)group * H * W) + lane32;
  float4* __restrict__ yout = (float4*)(out + (size_t)group * H * W) + lane32;

  float4 cm = make_float4(-FLT_MAX, -FLT_MAX, -FLT_MAX, -FLT_MAX);

#pragma unroll 4
  for (int h = H - 1; h >= 0; --h) {
    float4 v = xin[h * WV];
    // H-direction running suffix max (per column)
    cm.x = fmaxf(cm.x, v.x);
    cm.y = fmaxf(cm.y, v.y);
    cm.z = fmaxf(cm.z, v.z);
    cm.w = fmaxf(cm.w, v.w);

    // W-direction suffix max within this row.
    // intra-lane: m_k = max(cm_k .. cm_3)
    float m3 = cm.w;
    float m2 = fmaxf(cm.z, m3);
    float m1 = fmaxf(cm.y, m2);
    float m0 = fmaxf(cm.x, m1);

    // cross-lane inclusive suffix max over the 32-lane group
    // (shfl_down clamps at the width-32 boundary, returning own value,
    //  which is a no-op under max)
    float g = m0;
    g = fmaxf(g, __shfl_down(g, 1, 32));
    g = fmaxf(g, __shfl_down(g, 2, 32));
    g = fmaxf(g, __shfl_down(g, 4, 32));
    g = fmaxf(g, __shfl_down(g, 8, 32));
    g = fmaxf(g, __shfl_down(g, 16, 32));

    // exclusive suffix (strictly-greater lanes); last lane has none
    float e = __shfl_down(g, 1, 32);
    if (lane32 == 31) e = -FLT_MAX;

    float4 r;
    r.x = g;  // == max(m0, e)
    r.y = fmaxf(m1, e);
    r.z = fmaxf(m2, e);
    r.w = fmaxf(m3, e);

    // out = y + y
    r.x += r.x;
    r.y += r.y;
    r.z += r.z;
    r.w += r.w;
    yout[h * WV] = r;
  }
}

extern "C" void kernel_launch(void* const* d_in, const int* in_sizes, int n_in,
                              void* d_out, int out_size, void* d_ws,
                              size_t ws_size, hipStream_t stream) {
  const float* x = (const float*)d_in[0];
  float* out = (float*)d_out;

  const int plane_elems = 128 * 128;
  const int planes = in_sizes[0] / plane_elems;  // 4096

  const int block = 256;                 // 8 half-wave groups per block
  const int groups_per_block = block / 32;
  const int grid = (planes + groups_per_block - 1) / groups_per_block;  // 512

  corner_pool_kernel<<<grid, block, 0, stream>>>(x, out, planes);
}

// Round 2
// 429.650 us; speedup vs baseline: 1.0029x; 1.0029x over previous
//
#include <hip/hip_runtime.h>
#include <float.h>

// Top-left corner pooling, fused: out = 2 * rev_cummax_W(rev_cummax_H(x))
// x: (16, 256, 128, 128) fp32 NCHW -> 4096 independent 128x128 planes.
//
// Round-2 change: the W-direction cross-lane suffix scan is now pure-VALU
// DPP (row_shr + row_bcast15) instead of __shfl_down/ds_bpermute. The LDS
// pipe round trips (~100+ cyc each, 6 serialized per row) were the Round-1
// bottleneck (431 us vs ~85 us roofline).
//
// DPP scans run FORWARD across lanes, so lanes are REVERSED vs columns:
// lane j of a 32-lane half-wave holds the float4 at vector index 31-j
// (columns 124-4j .. 127-4j). Column suffix-max == lane prefix-max.
// The scan idiom (row_shr:1/2/4/8 + row_bcast:15 rows{1,3}) is segmented
// at 32 lanes, so the two planes sharing a wave64 never mix. Exclusive
// prefix via wave_shr:1 + cndmask at segment start (lane 32 would read
// lane 31 = other plane).

#define DPP_ROW_SHR1 0x111
#define DPP_ROW_SHR2 0x112
#define DPP_ROW_SHR4 0x114
#define DPP_ROW_SHR8 0x118
#define DPP_ROW_BCAST15 0x142
#define DPP_WAVE_SHR1 0x138

template <int CTRL, int ROW_MASK>
__device__ __forceinline__ float dpp_mov_f(float src) {
  // old = -FLT_MAX: lanes with no valid source (or rows masked off) get the
  // max-identity, so fmaxf(x, dpp(...)) is a no-op there.
  const int old = (int)0xFF7FFFFFu;  // bit pattern of -FLT_MAX
  int r = __builtin_amdgcn_update_dpp(old, __builtin_bit_cast(int, src),
                                      CTRL, ROW_MASK, 0xF, false);
  return __builtin_bit_cast(float, r);
}

__global__ __launch_bounds__(256) void corner_pool_kernel(
    const float* __restrict__ x, float* __restrict__ out, int planes) {
  constexpr int H = 128;
  constexpr int W = 128;
  constexpr int WV = W / 4;  // float4s per row = 32

  const int lane32 = threadIdx.x & 31;
  const int group = (blockIdx.x * blockDim.x + threadIdx.x) >> 5;
  if (group >= planes) return;

  const int rv = 31 - lane32;  // reversed vector index within the row
  const float4* __restrict__ xin =
      (const float4*)(x + (size_t)group * H * W) + rv;
  float4* __restrict__ yout = (float4*)(out + (size_t)group * H * W) + rv;

  const float NINF = -FLT_MAX;
  float4 cm = make_float4(NINF, NINF, NINF, NINF);
  const bool seg_start = (lane32 == 0);

#pragma unroll 4
  for (int h = H - 1; h >= 0; --h) {
    float4 v = xin[h * WV];
    // H-direction running suffix max (per column, loop-carried)
    cm.x = fmaxf(cm.x, v.x);
    cm.y = fmaxf(cm.y, v.y);
    cm.z = fmaxf(cm.z, v.z);
    cm.w = fmaxf(cm.w, v.w);

    // Intra-lane suffix max over ascending columns x..w
    float mw = cm.w;
    float mz = fmaxf(cm.z, mw);
    float my = fmaxf(cm.y, mz);
    float mx = fmaxf(cm.x, my);  // lane max M

    // Inclusive lane-prefix max over the 32-lane segment (pure VALU DPP)
    float g = mx;
    g = fmaxf(g, dpp_mov_f<DPP_ROW_SHR1, 0xF>(g));
    g = fmaxf(g, dpp_mov_f<DPP_ROW_SHR2, 0xF>(g));
    g = fmaxf(g, dpp_mov_f<DPP_ROW_SHR4, 0xF>(g));
    g = fmaxf(g, dpp_mov_f<DPP_ROW_SHR8, 0xF>(g));
    // rows 1 & 3 pick up lane 15 / lane 47 totals -> segmented at 32
    g = fmaxf(g, dpp_mov_f<DPP_ROW_BCAST15, 0xA>(g));

    // Exclusive prefix: shift inclusive by one lane across the wave,
    // then kill the value at each 32-lane segment start (lane 0 gets
    // -inf from bound_ctrl old; lane 32 must not see lane 31).
    float e = dpp_mov_f<DPP_WAVE_SHR1, 0xF>(g);
    e = seg_start ? NINF : e;

    float4 r;
    r.x = g;  // == max(mx, e)
    r.y = fmaxf(my, e);
    r.z = fmaxf(mz, e);
    r.w = fmaxf(mw, e);

    // out = y + y
    r.x += r.x;
    r.y += r.y;
    r.z += r.z;
    r.w += r.w;
    yout[h * WV] = r;
  }
}

extern "C" void kernel_launch(void* const* d_in, const int* in_sizes, int n_in,
                              void* d_out, int out_size, void* d_ws,
                              size_t ws_size, hipStream_t stream) {
  const float* x = (const float*)d_in[0];
  float* out = (float*)d_out;

  const int plane_elems = 128 * 128;
  const int planes = in_sizes[0] / plane_elems;  // 4096

  const int block = 256;  // 8 half-wave groups (8 planes) per block
  const int groups_per_block = block / 32;
  const int grid = (planes + groups_per_block - 1) / groups_per_block;  // 512

  corner_pool_kernel<<<grid, block, 0, stream>>>(x, out, planes);
}